// Round 1
// 365.285 us; speedup vs baseline: 1.2250x; 1.2250x over previous
//
#include <hip/hip_runtime.h>

typedef unsigned short u16;
typedef __attribute__((ext_vector_type(8))) short bf16x8;
typedef __attribute__((ext_vector_type(4))) float f32x4;
typedef __attribute__((ext_vector_type(4))) int i32x4;
typedef __attribute__((ext_vector_type(2))) int i32x2;

#define N_PTS   65536
#define CH_DIM  256
#define BATCH   8
#define KTOK    256
#define CTX_DIM 768
#define NHEAD   8
#define HD      64
#define HDIM    512   // NHEAD*HD
#define NPB     8192  // N_PTS/BATCH

__device__ __forceinline__ u16 f2bf(float f) {
    union { float f; unsigned u; } v; v.f = f;
    unsigned r = v.u + 0x7fffu + ((v.u >> 16) & 1u);
    return (u16)(r >> 16);
}

// async global->LDS, 16B per lane. LDS dest must be wave-uniform base + lane*16
// (our staging index is linear in tid, so this holds per wave).
__device__ __forceinline__ void gll16(const void* g, void* l) {
    __builtin_amdgcn_global_load_lds(
        (const __attribute__((address_space(1))) void*)g,
        (__attribute__((address_space(3))) void*)l, 16, 0, 0);
}

// ---------------------------------------------------------------------------
// convk: fp32 -> bf16, 8 elems/thread/iter (32B in / 16B out per lane).
// ---------------------------------------------------------------------------
__global__ void convk(const float* __restrict__ src, u16* __restrict__ dst, int n8) {
    int i = blockIdx.x * blockDim.x + threadIdx.x;
    int st = gridDim.x * blockDim.x;
    for (; i < n8; i += st) {
        const float* p = src + (size_t)i * 8;
        f32x4 a = *(const f32x4*)p;
        f32x4 b = *(const f32x4*)(p + 4);
        union { u16 h[8]; i32x4 q; } pk;
#pragma unroll
        for (int j = 0; j < 4; j++) { pk.h[j] = f2bf(a[j]); pk.h[4 + j] = f2bf(b[j]); }
        *(i32x4*)&dst[(size_t)i * 8] = pk.q;
    }
}

// ---------------------------------------------------------------------------
// tconvk: W[R][C] fp32 -> WT[C][R] bf16. Output-coalesced; weights are tiny
// and L2-resident so the strided reads don't matter.
// ---------------------------------------------------------------------------
__global__ void tconvk(const float* __restrict__ W, u16* __restrict__ WT, int R, int C) {
    int i = blockIdx.x * blockDim.x + threadIdx.x;
    if (i >= R * C) return;
    int c = i / R, r = i - c * R;
    WT[(size_t)c * R + r] = f2bf(W[(size_t)r * C + c]);
}

// ---------------------------------------------------------------------------
// gemm_bt (m97-class): C(MxN) = A(MxK) @ BT(NxK)^T, both bf16, fp32 accum.
// 128x128 tile, BK=32, 4 waves 2x2, 4x4 frags/wave.
// Staging: 4x global_load_lds dwordx4 per thread per K-step (2 for A, 2 for B),
// linear LDS (no pad -- global_load_lds requirement), zero staging VALU.
//   OUT_F32: fp32 out + fp32 bias/resid epilogue, else bf16 out.
//   VT_OUT:  (v-proj) write C transposed per (scene,head):
//            CT[((b*8+h)*64 + d)*256 + j] = C[row=b*256+j][col=h*64+d]
// MFMA 16x16x32 bf16 layouts (HW-verified, learn_hip m89/m91).
// ---------------------------------------------------------------------------
template <bool OUT_F32, bool VT_OUT>
__global__ __launch_bounds__(256, 3) void gemm_bt(
    const u16* __restrict__ A, const u16* __restrict__ BT, void* __restrict__ Cv,
    int M, int N, int K,
    const float* __restrict__ bias, const float* __restrict__ resid)
{
    __shared__ __align__(16) u16 As[128 * 32];   // 8 KB, A[m][k] tile
    __shared__ __align__(16) u16 Bs[128 * 32];   // 8 KB, BT[n][k] tile

    const int tid  = threadIdx.x;
    const int lane = tid & 63;
    const int w    = tid >> 6;
    const int wm   = w & 1;
    const int wn   = w >> 1;
    const int n0   = blockIdx.x * 128;
    const int m0   = blockIdx.y * 128;
    const int l15  = lane & 15;
    const int quad = lane >> 4;

    f32x4 acc[4][4];
#pragma unroll
    for (int i = 0; i < 4; i++)
#pragma unroll
        for (int j = 0; j < 4; j++) { acc[i][j][0]=0.f; acc[i][j][1]=0.f; acc[i][j][2]=0.f; acc[i][j][3]=0.f; }

    // staging map: 512 segments of 16B per tile; thread t owns segs t and t+256.
    // seg s -> row s>>2, u16-col (s&3)*8
    const int sr = tid >> 2;
    const int sc = (tid & 3) * 8;
    const u16* Abase = A  + (size_t)(m0 + sr) * K + sc;
    const u16* Bbase = BT + (size_t)(n0 + sr) * K + sc;
    u16* AsD = &As[tid * 8];
    u16* BsD = &Bs[tid * 8];
    const size_t rowStep = (size_t)64 * K;   // +64 rows for the second segment

    for (int k0 = 0; k0 < K; k0 += 32) {
        gll16(Abase + k0,           AsD);
        gll16(Abase + k0 + rowStep, AsD + 2048);
        gll16(Bbase + k0,           BsD);
        gll16(Bbase + k0 + rowStep, BsD + 2048);
        __syncthreads();   // compiler emits vmcnt(0) drain before barrier

        bf16x8 af[4], bfr[4];
#pragma unroll
        for (int rt = 0; rt < 4; rt++)
            af[rt] = *(const bf16x8*)&As[(wm * 64 + rt * 16 + l15) * 32 + quad * 8];
#pragma unroll
        for (int nt = 0; nt < 4; nt++)
            bfr[nt] = *(const bf16x8*)&Bs[(wn * 64 + nt * 16 + l15) * 32 + quad * 8];
#pragma unroll
        for (int rt = 0; rt < 4; rt++)
#pragma unroll
            for (int nt = 0; nt < 4; nt++)
                acc[rt][nt] = __builtin_amdgcn_mfma_f32_16x16x32_bf16(af[rt], bfr[nt], acc[rt][nt], 0, 0, 0);
        __syncthreads();
    }

    // ---- epilogue ----
    if (VT_OUT) {
        u16* CT = (u16*)Cv;
#pragma unroll
        for (int nt = 0; nt < 4; nt++) {
            int col = n0 + wn * 64 + nt * 16 + l15;   // h*64 + d
            int hh = col >> 6, dd = col & 63;
#pragma unroll
            for (int rt = 0; rt < 4; rt++) {
                int row = m0 + wm * 64 + rt * 16 + quad * 4;  // b*256 + j (j%4==0)
                int bb = row >> 8, jb = row & 255;
                union { u16 h[4]; i32x2 q; } pk;
#pragma unroll
                for (int r = 0; r < 4; r++) pk.h[r] = f2bf(acc[rt][nt][r]);
                *(i32x2*)&CT[(((size_t)(bb * 8 + hh)) * 64 + dd) * 256 + jb] = pk.q;
            }
        }
    } else {
#pragma unroll
        for (int nt = 0; nt < 4; nt++) {
            int col = n0 + wn * 64 + nt * 16 + l15;
            float bv = bias ? bias[col] : 0.0f;
#pragma unroll
            for (int rt = 0; rt < 4; rt++) {
#pragma unroll
                for (int r = 0; r < 4; r++) {
                    int row = m0 + wm * 64 + rt * 16 + quad * 4 + r;
                    float v = acc[rt][nt][r] + bv;
                    if (resid) v += resid[(size_t)row * N + col];
                    if (OUT_F32) ((float*)Cv)[(size_t)row * N + col] = v;
                    else         ((u16*)Cv)[(size_t)row * N + col]   = f2bf(v);
                }
            }
        }
    }
}

// ---------------------------------------------------------------------------
// MFMA attention (unchanged this round). grid = (NPB/64, BATCH*NHEAD), block 256.
// V arrives PRE-TRANSPOSED (vbufT[b][h][d][j]) -> Vt staging is contiguous
// b128 LDS writes. LDS: max(Ks 36864, Vt 33792) + Ps 9216 = 46080 B.
// ft aliases qbuf (read strictly before write, same block, disjoint blocks).
// ---------------------------------------------------------------------------
#define KS2 72    // Ks row stride
#define VS2 264   // Vt row stride
#define PS2 72    // Ps row stride
__global__ __launch_bounds__(256, 3) void attn_mfma(
    const u16* qbuf, const u16* __restrict__ kbuf,
    const u16* __restrict__ vbufT, const int* __restrict__ perm,
    u16* ft)
{
    __shared__ __align__(16) u16 smem[23040];   // 46080 B
    u16* Ks = smem;                              // phase 1   (36864 B)
    u16* Vt = smem;                              // phases 3-4 (33792 B, reuse)
    u16* Ps = smem + 18432;                      // phase 4   (9216 B)

    const int tid   = threadIdx.x;
    const int lane  = tid & 63;
    const int w     = tid >> 6;
    const int chunk = blockIdx.x;
    const int bh    = blockIdx.y;
    const int b     = bh >> 3;
    const int h     = bh & 7;
    const int l15   = lane & 15;
    const int quad  = lane >> 4;

    // ---- Q A-frags straight from global (gathered row, 16B contiguous) ----
    const int prow = perm[b * NPB + chunk * 64 + w * 16 + l15];
    const u16* qrow = qbuf + (size_t)prow * HDIM + h * HD;
    bf16x8 af0 = *(const bf16x8*)&qrow[quad * 8];
    bf16x8 af1 = *(const bf16x8*)&qrow[32 + quad * 8];

    // ---- stage K_h (256x64) into LDS, b128 writes ----
    {
        const int j8 = tid >> 3;        // 0..31
        const int c  = (tid & 7) * 8;   // 0..56
#pragma unroll
        for (int pass = 0; pass < 8; pass++) {
            int jj = j8 + pass * 32;
            i32x4 val = *(const i32x4*)&kbuf[((size_t)(b * KTOK + jj)) * HDIM + h * HD + c];
            *(i32x4*)&Ks[jj * KS2 + c] = val;
        }
    }
    __syncthreads();

    // ---- phase 1: S = Q K^T (32 MFMA/wave) ----
    f32x4 sc[16];
#pragma unroll
    for (int nt = 0; nt < 16; nt++) { sc[nt][0]=0.f; sc[nt][1]=0.f; sc[nt][2]=0.f; sc[nt][3]=0.f; }
#pragma unroll
    for (int nt = 0; nt < 16; nt++) {
        bf16x8 bk0 = *(const bf16x8*)&Ks[(nt * 16 + l15) * KS2 + quad * 8];
        sc[nt] = __builtin_amdgcn_mfma_f32_16x16x32_bf16(af0, bk0, sc[nt], 0, 0, 0);
    }
#pragma unroll
    for (int nt = 0; nt < 16; nt++) {
        bf16x8 bk1 = *(const bf16x8*)&Ks[(nt * 16 + l15) * KS2 + 32 + quad * 8];
        sc[nt] = __builtin_amdgcn_mfma_f32_16x16x32_bf16(af1, bk1, sc[nt], 0, 0, 0);
    }
    __syncthreads();   // all waves done reading Ks; region becomes Vt

    // ---- phase 3a: load V^T slice (64 d x 256 j) from vbufT into regs ----
    i32x4 vreg[8];
    const u16* vslice = vbufT + ((size_t)(b * NHEAD + h)) * HD * KTOK;
    const int vrow = tid >> 2;          // d = 0..63
    const int vc0  = (tid & 3) * 8;     // j chunk base within 32-elem group
#pragma unroll
    for (int pass = 0; pass < 8; pass++)
        vreg[pass] = *(const i32x4*)&vslice[(size_t)vrow * KTOK + vc0 + pass * 32];

    // ---- phase 2: softmax over 256 cols, in registers ----
#pragma unroll
    for (int r = 0; r < 4; r++) {
        float m = -1e30f;
#pragma unroll
        for (int nt = 0; nt < 16; nt++) { sc[nt][r] *= 0.125f; m = fmaxf(m, sc[nt][r]); }
#pragma unroll
        for (int off = 8; off >= 1; off >>= 1) m = fmaxf(m, __shfl_xor(m, off));
        float s = 0.f;
#pragma unroll
        for (int nt = 0; nt < 16; nt++) { float e = __expf(sc[nt][r] - m); sc[nt][r] = e; s += e; }
#pragma unroll
        for (int off = 8; off >= 1; off >>= 1) s += __shfl_xor(s, off);
        float inv = 1.0f / s;
#pragma unroll
        for (int nt = 0; nt < 16; nt++) sc[nt][r] *= inv;
    }

    // ---- phase 3b: store Vt rows to LDS (contiguous b128, no transpose) ----
#pragma unroll
    for (int pass = 0; pass < 8; pass++)
        *(i32x4*)&Vt[vrow * VS2 + vc0 + pass * 32] = vreg[pass];
    __syncthreads();

    // ---- phase 4: O = P V  (4 chunks of 64 j; 8 MFMA/wave each) ----
    f32x4 o[4];
#pragma unroll
    for (int n = 0; n < 4; n++) { o[n][0]=0.f; o[n][1]=0.f; o[n][2]=0.f; o[n][3]=0.f; }

    for (int c4 = 0; c4 < 4; c4++) {
#pragma unroll
        for (int n = 0; n < 4; n++) {
#pragma unroll
            for (int r = 0; r < 4; r++)
                Ps[(w * 16 + quad * 4 + r) * PS2 + n * 16 + l15] = f2bf(sc[c4 * 4 + n][r]);
        }
        __syncthreads();
#pragma unroll
        for (int ks = 0; ks < 2; ks++) {
            bf16x8 ap = *(const bf16x8*)&Ps[(w * 16 + l15) * PS2 + ks * 32 + quad * 8];
#pragma unroll
            for (int n = 0; n < 4; n++) {
                bf16x8 bv = *(const bf16x8*)&Vt[(n * 16 + l15) * VS2 + c4 * 64 + ks * 32 + quad * 8];
                o[n] = __builtin_amdgcn_mfma_f32_16x16x32_bf16(ap, bv, o[n], 0, 0, 0);
            }
        }
        __syncthreads();
    }

    // ---- phase 5: scatter O rows to ft[perm[q]] (head-h slice) ----
#pragma unroll
    for (int r = 0; r < 4; r++) {
        int po = perm[b * NPB + chunk * 64 + w * 16 + quad * 4 + r];
        u16* frow = ft + (size_t)po * HDIM + h * HD;
#pragma unroll
        for (int n = 0; n < 4; n++)
            frow[n * 16 + l15] = f2bf(o[n][r]);
    }
}

// ---------------------------------------------------------------------------
// Launch.
// Workspace (unchanged 71303168 B):
//   ws+0        kbuf  [2048][512] bf16          (2 MB)
//   ws+2097152  vbufT [b][h][d][j] bf16         (2 MB)  -> WoutT after attn
//   ws+4194304  qbuf/ft [65536][512] bf16       (67 MB)
// Scratch in d_out (all dead before the final gemm writes d_out):
//   +0          xb  [65536][256] bf16           (33.5 MB)
//   +33554432   cb  [2048][768]  bf16           (3 MB)
//   +36700160   WqT [512][256]   bf16
//   +36962304   WkT [512][768]   bf16
//   +37748736   WvT [512][768]   bf16           (ends 38535168 < 67108864)
// ---------------------------------------------------------------------------
extern "C" void kernel_launch(void* const* d_in, const int* in_sizes, int n_in,
                              void* d_out, int out_size, void* d_ws, size_t ws_size,
                              hipStream_t stream) {
    const float* xF      = (const float*)d_in[0];
    const float* context = (const float*)d_in[1];
    const int*   perm    = (const int*)d_in[2];
    const float* Wq      = (const float*)d_in[3];
    const float* Wk      = (const float*)d_in[4];
    const float* Wv      = (const float*)d_in[5];
    const float* Wout    = (const float*)d_in[6];
    const float* b_out   = (const float*)d_in[7];
    float*       out     = (float*)d_out;

    const size_t WS_NEED = 71303168ULL;
    if (ws_size < WS_NEED) {
        hipMemsetAsync(d_out, 0, (size_t)out_size * sizeof(float), stream);
        return;
    }
    char* ws    = (char*)d_ws;
    u16* kbuf   = (u16*)(ws + 0);
    u16* vbufT  = (u16*)(ws + 2097152);
    u16* qbuf   = (u16*)(ws + 4194304);
    u16* ft     = qbuf;                         // aliased (see attn_mfma comment)
    u16* WoutT  = (u16*)(ws + 2097152);         // overwrites vbufT AFTER attn

    char* ob    = (char*)d_out;                 // d_out as pre-attn scratch
    u16* xb     = (u16*)(ob + 0);
    u16* cb     = (u16*)(ob + 33554432);
    u16* WqT    = (u16*)(ob + 36700160);
    u16* WkT    = (u16*)(ob + 36962304);
    u16* WvT    = (u16*)(ob + 37748736);

    // ---- prep: bf16 conversions / weight transposes ----
    convk<<<2048, 256, 0, stream>>>(xF, xb, N_PTS * CH_DIM / 8);
    convk<<<768, 256, 0, stream>>>(context, cb, BATCH * KTOK * CTX_DIM / 8);
    tconvk<<<(CH_DIM * HDIM + 255) / 256, 256, 0, stream>>>(Wq, WqT, CH_DIM, HDIM);
    tconvk<<<(CTX_DIM * HDIM + 255) / 256, 256, 0, stream>>>(Wk, WkT, CTX_DIM, HDIM);
    tconvk<<<(CTX_DIM * HDIM + 255) / 256, 256, 0, stream>>>(Wv, WvT, CTX_DIM, HDIM);

    // ---- projections (m97-class bf16 gemm, global_load_lds staging) ----
    gemm_bt<false, false><<<dim3(HDIM / 128, N_PTS / 128), 256, 0, stream>>>(
        xb, WqT, qbuf, N_PTS, HDIM, CH_DIM, nullptr, nullptr);
    gemm_bt<false, false><<<dim3(HDIM / 128, (BATCH * KTOK) / 128), 256, 0, stream>>>(
        cb, WkT, kbuf, BATCH * KTOK, HDIM, CTX_DIM, nullptr, nullptr);
    gemm_bt<false, true><<<dim3(HDIM / 128, (BATCH * KTOK) / 128), 256, 0, stream>>>(
        cb, WvT, vbufT, BATCH * KTOK, HDIM, CTX_DIM, nullptr, nullptr);

    // ---- attention ----
    attn_mfma<<<dim3(NPB / 64, BATCH * NHEAD), 256, 0, stream>>>(
        qbuf, kbuf, vbufT, perm, ft);

    // ---- out projection (+bias+residual, fp32 out) ----
    tconvk<<<(HDIM * CH_DIM + 255) / 256, 256, 0, stream>>>(Wout, WoutT, HDIM, CH_DIM);
    gemm_bt<true, false><<<dim3(CH_DIM / 128, N_PTS / 128), 256, 0, stream>>>(
        ft, WoutT, out, N_PTS, CH_DIM, HDIM, b_out, xF);
}

// Round 2
// 331.294 us; speedup vs baseline: 1.3507x; 1.1026x over previous
//
#include <hip/hip_runtime.h>

typedef unsigned short u16;
typedef __attribute__((ext_vector_type(8))) short bf16x8;
typedef __attribute__((ext_vector_type(4))) float f32x4;
typedef __attribute__((ext_vector_type(4))) int i32x4;
typedef __attribute__((ext_vector_type(2))) int i32x2;

#define N_PTS   65536
#define CH_DIM  256
#define BATCH   8
#define KTOK    256
#define CTX_DIM 768
#define NHEAD   8
#define HD      64
#define HDIM    512   // NHEAD*HD
#define NPB     8192  // N_PTS/BATCH

__device__ __forceinline__ u16 f2bf(float f) {
    union { float f; unsigned u; } v; v.f = f;
    unsigned r = v.u + 0x7fffu + ((v.u >> 16) & 1u);
    return (u16)(r >> 16);
}
__device__ __forceinline__ unsigned pk2bf(float lo, float hi) {
    return (unsigned)f2bf(lo) | ((unsigned)f2bf(hi) << 16);
}

// async global->LDS, 16B per lane. LDS dest must be wave-uniform base + lane*16
// (our staging index is linear in tid, so this holds per wave).
__device__ __forceinline__ void gll16(const void* g, void* l) {
    __builtin_amdgcn_global_load_lds(
        (const __attribute__((address_space(1))) void*)g,
        (__attribute__((address_space(3))) void*)l, 16, 0, 0);
}

// ---------------------------------------------------------------------------
// convk: fp32 -> bf16, 8 elems/thread/iter (32B in / 16B out per lane).
// ---------------------------------------------------------------------------
__global__ void convk(const float* __restrict__ src, u16* __restrict__ dst, int n8) {
    int i = blockIdx.x * blockDim.x + threadIdx.x;
    int st = gridDim.x * blockDim.x;
    for (; i < n8; i += st) {
        const float* p = src + (size_t)i * 8;
        f32x4 a = *(const f32x4*)p;
        f32x4 b = *(const f32x4*)(p + 4);
        union { u16 h[8]; i32x4 q; } pk;
#pragma unroll
        for (int j = 0; j < 4; j++) { pk.h[j] = f2bf(a[j]); pk.h[4 + j] = f2bf(b[j]); }
        *(i32x4*)&dst[(size_t)i * 8] = pk.q;
    }
}

// ---------------------------------------------------------------------------
// tconvk: W[R][C] fp32 -> WT[C][R] bf16.
// ---------------------------------------------------------------------------
__global__ void tconvk(const float* __restrict__ W, u16* __restrict__ WT, int R, int C) {
    int i = blockIdx.x * blockDim.x + threadIdx.x;
    if (i >= R * C) return;
    int c = i / R, r = i - c * R;
    WT[(size_t)c * R + r] = f2bf(W[(size_t)r * C + c]);
}

// ---------------------------------------------------------------------------
// gemm_bt (m97-class): C(MxN) = A(MxK) @ BT(NxK)^T, both bf16, fp32 accum.
// 128x128 tile, BK=32, 4 waves 2x2, 4x4 frags/wave, global_load_lds staging.
//   OUT_F32: fp32 out + fp32 bias/resid epilogue, else bf16 out (scaled by oscale).
//   VT_OUT:  (v-proj) write C transposed per (scene,head) with PERMUTED column
//            order g: token t -> col c' = (t&0xE0)|((t&0x0C)<<1)|((t&0x10)>>2)|(t&3)
//            so attention's PV B-fragments read Vt' contiguously while P stays
//            entirely in registers (zero-shuffle P path; see attn_mfma).
// T1 XCD swizzle: bijective remap (all grids here have nwg % 8 == 0).
// ---------------------------------------------------------------------------
template <bool OUT_F32, bool VT_OUT>
__global__ __launch_bounds__(256, 3) void gemm_bt(
    const u16* __restrict__ A, const u16* __restrict__ BT, void* __restrict__ Cv,
    int M, int N, int K,
    const float* __restrict__ bias, const float* __restrict__ resid, float oscale)
{
    __shared__ __align__(16) u16 As[128 * 32];   // 8 KB, A[m][k] tile
    __shared__ __align__(16) u16 Bs[128 * 32];   // 8 KB, BT[n][k] tile

    const int tid  = threadIdx.x;
    const int lane = tid & 63;
    const int w    = tid >> 6;
    const int wm   = w & 1;
    const int wn   = w >> 1;

    // XCD-aware bijective swizzle (T1): consecutive work chunks stay on one XCD's L2.
    const int nwg = gridDim.x * gridDim.y;
    const int wg  = blockIdx.y * gridDim.x + blockIdx.x;
    const int swz = (wg & 7) * (nwg >> 3) + (wg >> 3);
    const int n0  = (swz % gridDim.x) * 128;
    const int m0  = (swz / gridDim.x) * 128;

    const int l15  = lane & 15;
    const int quad = lane >> 4;

    f32x4 acc[4][4];
#pragma unroll
    for (int i = 0; i < 4; i++)
#pragma unroll
        for (int j = 0; j < 4; j++) { acc[i][j][0]=0.f; acc[i][j][1]=0.f; acc[i][j][2]=0.f; acc[i][j][3]=0.f; }

    const int sr = tid >> 2;
    const int sc = (tid & 3) * 8;
    const u16* Abase = A  + (size_t)(m0 + sr) * K + sc;
    const u16* Bbase = BT + (size_t)(n0 + sr) * K + sc;
    u16* AsD = &As[tid * 8];
    u16* BsD = &Bs[tid * 8];
    const size_t rowStep = (size_t)64 * K;

    for (int k0 = 0; k0 < K; k0 += 32) {
        gll16(Abase + k0,           AsD);
        gll16(Abase + k0 + rowStep, AsD + 2048);
        gll16(Bbase + k0,           BsD);
        gll16(Bbase + k0 + rowStep, BsD + 2048);
        __syncthreads();

        bf16x8 af[4], bfr[4];
#pragma unroll
        for (int rt = 0; rt < 4; rt++)
            af[rt] = *(const bf16x8*)&As[(wm * 64 + rt * 16 + l15) * 32 + quad * 8];
#pragma unroll
        for (int nt = 0; nt < 4; nt++)
            bfr[nt] = *(const bf16x8*)&Bs[(wn * 64 + nt * 16 + l15) * 32 + quad * 8];
#pragma unroll
        for (int rt = 0; rt < 4; rt++)
#pragma unroll
            for (int nt = 0; nt < 4; nt++)
                acc[rt][nt] = __builtin_amdgcn_mfma_f32_16x16x32_bf16(af[rt], bfr[nt], acc[rt][nt], 0, 0, 0);
        __syncthreads();
    }

    // ---- epilogue ----
    if (VT_OUT) {
        u16* CT = (u16*)Cv;
#pragma unroll
        for (int nt = 0; nt < 4; nt++) {
            int col = n0 + wn * 64 + nt * 16 + l15;   // h*64 + d
            int hh = col >> 6, dd = col & 63;
#pragma unroll
            for (int rt = 0; rt < 4; rt++) {
                int row = m0 + wm * 64 + rt * 16 + quad * 4;  // b*256 + t (t%4==0)
                int bb = row >> 8, jb = row & 255;
                // permuted column base c' = g^-1(token): bits [7:5]=ks, [4:3]=qa, [2]=b, [1:0]=a
                int jp = (jb & 0xE0) | ((jb & 0x0C) << 1) | ((jb & 0x10) >> 2);
                union { u16 h[4]; i32x2 q; } pk;
#pragma unroll
                for (int r = 0; r < 4; r++) pk.h[r] = f2bf(acc[rt][nt][r]);
                *(i32x2*)&CT[(((size_t)(bb * 8 + hh)) * 64 + dd) * 256 + jp] = pk.q;
            }
        }
    } else {
#pragma unroll
        for (int nt = 0; nt < 4; nt++) {
            int col = n0 + wn * 64 + nt * 16 + l15;
            float bv = bias ? bias[col] : 0.0f;
#pragma unroll
            for (int rt = 0; rt < 4; rt++) {
#pragma unroll
                for (int r = 0; r < 4; r++) {
                    int row = m0 + wm * 64 + rt * 16 + quad * 4 + r;
                    float v = acc[rt][nt][r] + bv;
                    if (resid) v += resid[(size_t)row * N + col];
                    if (OUT_F32) ((float*)Cv)[(size_t)row * N + col] = v;
                    else         ((u16*)Cv)[(size_t)row * N + col]   = f2bf(v * oscale);
                }
            }
        }
    }
}

// ---------------------------------------------------------------------------
// MFMA attention, zero-shuffle P path.
//   QK^T computed SWAPPED: S^T = mfma(K, Q) -> lane holds q=l15's scores at
//   k = 16*nt + 4*quad + r. Softmax is lane-local + 2 cross-quad shuffles.
//   PV uses P directly from registers as the A-fragment under the k-bijection
//   f(ks, 8q+j) = 32ks + 16(j>>2) + 4q + (j&3); V arrives with columns already
//   permuted by g = f (baked into the V-proj epilogue), so B-fragments are
//   plain contiguous b128 LDS reads. No Ps buffer, 3 barriers total.
//   1/s normalization deferred to the O epilogue (per-q inv via shuffle).
//   0.125 scale pre-folded into Q (exact 2^-3, done in Q-proj epilogue).
// LDS: max(Ks 36864, Vt' 33792) = 36864 B -> 4 blocks/CU.
// ft aliases qbuf (each block reads exactly the q-rows/h-slice it writes;
// (b,chunk) row-sets disjoint, h column-slices disjoint).
// ---------------------------------------------------------------------------
#define KS2 72    // Ks row stride (u16): bank slot (l15+quad) uniform-8, conflict-free
#define VS2 264   // Vt row stride (u16): bank slot (l15+quad) uniform-8, conflict-free
__global__ __launch_bounds__(256, 4) void attn_mfma(
    const u16* qbuf, const u16* __restrict__ kbuf,
    const u16* __restrict__ vbufT, const int* __restrict__ perm,
    u16* ft)
{
    __shared__ __align__(16) u16 smem[18432];   // 36864 B
    u16* Ks = smem;                              // phase 1 (256 x KS2)
    u16* Vt = smem;                              // phase 3 (64 x VS2, reuse)

    const int tid   = threadIdx.x;
    const int lane  = tid & 63;
    const int w     = tid >> 6;
    const int chunk = blockIdx.x;
    const int bh    = blockIdx.y;
    const int b     = bh >> 3;
    const int h     = bh & 7;
    const int l15   = lane & 15;
    const int quad  = lane >> 4;

    // ---- Q B-frags from global (gathered row, 16B contiguous); q = w*16+l15 ----
    const int prow = perm[b * NPB + chunk * 64 + w * 16 + l15];
    const u16* qrow = qbuf + (size_t)prow * HDIM + h * HD;
    bf16x8 qf0 = *(const bf16x8*)&qrow[quad * 8];
    bf16x8 qf1 = *(const bf16x8*)&qrow[32 + quad * 8];

    // ---- stage K_h (256x64) into LDS, b128 writes ----
    {
        const int j8 = tid >> 3;        // 0..31
        const int c  = (tid & 7) * 8;   // 0..56
#pragma unroll
        for (int pass = 0; pass < 8; pass++) {
            int jj = j8 + pass * 32;
            i32x4 val = *(const i32x4*)&kbuf[((size_t)(b * KTOK + jj)) * HDIM + h * HD + c];
            *(i32x4*)&Ks[jj * KS2 + c] = val;
        }
    }
    __syncthreads();

    // ---- phase 1: S^T = K @ Q^T  (A = K-frag, B = Q-frag) ----
    f32x4 sc[16];
#pragma unroll
    for (int nt = 0; nt < 16; nt++) { sc[nt][0]=0.f; sc[nt][1]=0.f; sc[nt][2]=0.f; sc[nt][3]=0.f; }
#pragma unroll
    for (int nt = 0; nt < 16; nt++) {
        bf16x8 kf = *(const bf16x8*)&Ks[(nt * 16 + l15) * KS2 + quad * 8];
        sc[nt] = __builtin_amdgcn_mfma_f32_16x16x32_bf16(kf, qf0, sc[nt], 0, 0, 0);
    }
#pragma unroll
    for (int nt = 0; nt < 16; nt++) {
        bf16x8 kf = *(const bf16x8*)&Ks[(nt * 16 + l15) * KS2 + 32 + quad * 8];
        sc[nt] = __builtin_amdgcn_mfma_f32_16x16x32_bf16(kf, qf1, sc[nt], 0, 0, 0);
    }
    // sc[nt][r] = S[k = nt*16 + quad*4 + r][q = w*16 + l15]   (pre-scaled by 1/8 via Q)

    // ---- phase 3a: issue V' loads (64 d x 256 c') to regs; latency hides under softmax ----
    i32x4 vreg[8];
    const u16* vslice = vbufT + ((size_t)(b * NHEAD + h)) * HD * KTOK;
    const int vrow = tid >> 2;          // d = 0..63
    const int vc0  = (tid & 3) * 8;
#pragma unroll
    for (int pass = 0; pass < 8; pass++)
        vreg[pass] = *(const i32x4*)&vslice[(size_t)vrow * KTOK + vc0 + pass * 32];

    // ---- phase 2: softmax, lane-local (q = l15); unnormalized exp, deferred 1/s ----
    float m = -1e30f;
#pragma unroll
    for (int nt = 0; nt < 16; nt++) {
        f32x4 v = sc[nt];
        m = fmaxf(m, fmaxf(fmaxf(v[0], v[1]), fmaxf(v[2], v[3])));
    }
    m = fmaxf(m, __shfl_xor(m, 16));
    m = fmaxf(m, __shfl_xor(m, 32));
    float s = 0.f;
#pragma unroll
    for (int nt = 0; nt < 16; nt++) {
#pragma unroll
        for (int r = 0; r < 4; r++) { float e = __expf(sc[nt][r] - m); sc[nt][r] = e; s += e; }
    }
    s += __shfl_xor(s, 16);
    s += __shfl_xor(s, 32);
    float inv = 1.0f / s;

    // ---- pack P to bf16 pairs in-register (A-frag words under bijection f) ----
    unsigned up[16][2];
#pragma unroll
    for (int nt = 0; nt < 16; nt++) {
        up[nt][0] = pk2bf(sc[nt][0], sc[nt][1]);
        up[nt][1] = pk2bf(sc[nt][2], sc[nt][3]);
    }

    __syncthreads();   // all waves done reading Ks; region becomes Vt'

    // ---- phase 3b: store Vt' rows to LDS (contiguous b128) ----
#pragma unroll
    for (int pass = 0; pass < 8; pass++)
        *(i32x4*)&Vt[vrow * VS2 + vc0 + pass * 32] = vreg[pass];
    __syncthreads();

    // ---- phase 4: O = P V  (A = P regs, B = Vt' b128 reads; 32 MFMA) ----
    f32x4 o[4];
#pragma unroll
    for (int n = 0; n < 4; n++) { o[n][0]=0.f; o[n][1]=0.f; o[n][2]=0.f; o[n][3]=0.f; }

#pragma unroll
    for (int ks = 0; ks < 8; ks++) {
        union { unsigned u[4]; bf16x8 v; } pb;
        pb.u[0] = up[2 * ks][0];
        pb.u[1] = up[2 * ks][1];
        pb.u[2] = up[2 * ks + 1][0];
        pb.u[3] = up[2 * ks + 1][1];
#pragma unroll
        for (int nt = 0; nt < 4; nt++) {
            bf16x8 bv = *(const bf16x8*)&Vt[(nt * 16 + l15) * VS2 + ks * 32 + quad * 8];
            o[nt] = __builtin_amdgcn_mfma_f32_16x16x32_bf16(pb.v, bv, o[nt], 0, 0, 0);
        }
    }
    // o[nt][r] = O~[q = w*16 + quad*4 + r][d = nt*16 + l15]  (unnormalized)

    // ---- phase 5: normalize + scatter O rows to ft[perm[q]] (head-h slice) ----
#pragma unroll
    for (int r = 0; r < 4; r++) {
        float invq = __shfl(inv,  quad * 4 + r);
        int   po   = __shfl(prow, quad * 4 + r);
        u16* frow = ft + (size_t)po * HDIM + h * HD;
#pragma unroll
        for (int nt = 0; nt < 4; nt++)
            frow[nt * 16 + l15] = f2bf(o[nt][r] * invq);
    }
}

// ---------------------------------------------------------------------------
// Launch.
// Workspace (unchanged 71303168 B):
//   ws+0        kbuf  [2048][512] bf16          (2 MB)
//   ws+2097152  vbufT [b][h][d][c'] bf16        (2 MB)  -> WoutT after attn
//   ws+4194304  qbuf/ft [65536][512] bf16       (67 MB)
// Scratch in d_out (all dead before the final gemm writes d_out):
//   +0          xb  [65536][256] bf16           (33.5 MB)
//   +33554432   cb  [2048][768]  bf16           (3 MB)
//   +36700160   WqT / +36962304 WkT / +37748736 WvT   (ends 38535168 < 67108864)
// ---------------------------------------------------------------------------
extern "C" void kernel_launch(void* const* d_in, const int* in_sizes, int n_in,
                              void* d_out, int out_size, void* d_ws, size_t ws_size,
                              hipStream_t stream) {
    const float* xF      = (const float*)d_in[0];
    const float* context = (const float*)d_in[1];
    const int*   perm    = (const int*)d_in[2];
    const float* Wq      = (const float*)d_in[3];
    const float* Wk      = (const float*)d_in[4];
    const float* Wv      = (const float*)d_in[5];
    const float* Wout    = (const float*)d_in[6];
    const float* b_out   = (const float*)d_in[7];
    float*       out     = (float*)d_out;

    const size_t WS_NEED = 71303168ULL;
    if (ws_size < WS_NEED) {
        hipMemsetAsync(d_out, 0, (size_t)out_size * sizeof(float), stream);
        return;
    }
    char* ws    = (char*)d_ws;
    u16* kbuf   = (u16*)(ws + 0);
    u16* vbufT  = (u16*)(ws + 2097152);
    u16* qbuf   = (u16*)(ws + 4194304);
    u16* ft     = qbuf;                         // aliased (see attn_mfma comment)
    u16* WoutT  = (u16*)(ws + 2097152);         // overwrites vbufT AFTER attn

    char* ob    = (char*)d_out;                 // d_out as pre-attn scratch
    u16* xb     = (u16*)(ob + 0);
    u16* cb     = (u16*)(ob + 33554432);
    u16* WqT    = (u16*)(ob + 36700160);
    u16* WkT    = (u16*)(ob + 36962304);
    u16* WvT    = (u16*)(ob + 37748736);

    // ---- prep: bf16 conversions / weight transposes ----
    convk<<<2048, 256, 0, stream>>>(xF, xb, N_PTS * CH_DIM / 8);
    convk<<<768, 256, 0, stream>>>(context, cb, BATCH * KTOK * CTX_DIM / 8);
    tconvk<<<(CH_DIM * HDIM + 255) / 256, 256, 0, stream>>>(Wq, WqT, CH_DIM, HDIM);
    tconvk<<<(CTX_DIM * HDIM + 255) / 256, 256, 0, stream>>>(Wk, WkT, CTX_DIM, HDIM);
    tconvk<<<(CTX_DIM * HDIM + 255) / 256, 256, 0, stream>>>(Wv, WvT, CTX_DIM, HDIM);

    // ---- projections; Q pre-scaled by D^-0.5 = 0.125 (exact in bf16) ----
    gemm_bt<false, false><<<dim3(HDIM / 128, N_PTS / 128), 256, 0, stream>>>(
        xb, WqT, qbuf, N_PTS, HDIM, CH_DIM, nullptr, nullptr, 0.125f);
    gemm_bt<false, false><<<dim3(HDIM / 128, (BATCH * KTOK) / 128), 256, 0, stream>>>(
        cb, WkT, kbuf, BATCH * KTOK, HDIM, CTX_DIM, nullptr, nullptr, 1.0f);
    gemm_bt<false, true><<<dim3(HDIM / 128, (BATCH * KTOK) / 128), 256, 0, stream>>>(
        cb, WvT, vbufT, BATCH * KTOK, HDIM, CTX_DIM, nullptr, nullptr, 1.0f);

    // ---- attention ----
    attn_mfma<<<dim3(NPB / 64, BATCH * NHEAD), 256, 0, stream>>>(
        qbuf, kbuf, vbufT, perm, ft);

    // ---- out projection (+bias+residual, fp32 out) ----
    tconvk<<<(HDIM * CH_DIM + 255) / 256, 256, 0, stream>>>(Wout, WoutT, HDIM, CH_DIM);
    gemm_bt<true, false><<<dim3(CH_DIM / 128, N_PTS / 128), 256, 0, stream>>>(
        ft, WoutT, out, N_PTS, CH_DIM, HDIM, b_out, xF, 1.0f);
}

// Round 3
// 302.187 us; speedup vs baseline: 1.4807x; 1.0963x over previous
//
#include <hip/hip_runtime.h>

typedef unsigned short u16;
typedef __attribute__((ext_vector_type(8))) short bf16x8;
typedef __attribute__((ext_vector_type(4))) float f32x4;
typedef __attribute__((ext_vector_type(4))) int i32x4;
typedef __attribute__((ext_vector_type(2))) int i32x2;

#define N_PTS   65536
#define CH_DIM  256
#define BATCH   8
#define KTOK    256
#define CTX_DIM 768
#define NHEAD   8
#define HD      64
#define HDIM    512   // NHEAD*HD
#define NPB     8192  // N_PTS/BATCH

__device__ __forceinline__ u16 f2bf(float f) {
    union { float f; unsigned u; } v; v.f = f;
    unsigned r = v.u + 0x7fffu + ((v.u >> 16) & 1u);
    return (u16)(r >> 16);
}
// HW packed f32->bf16 (RNE), 1 instr for a pair.
__device__ __forceinline__ unsigned cvtpk(float lo, float hi) {
    unsigned r;
    asm("v_cvt_pk_bf16_f32 %0, %1, %2" : "=v"(r) : "v"(lo), "v"(hi));
    return r;
}
// bare v_exp_f32 (base-2 exponential)
__device__ __forceinline__ float exp2_hw(float x) {
    float r;
    asm("v_exp_f32 %0, %1" : "=v"(r) : "v"(x));
    return r;
}

// async global->LDS, 16B per lane. HW writes lane i at wave-uniform base + i*16.
__device__ __forceinline__ void gll16(const void* g, void* l) {
    __builtin_amdgcn_global_load_lds(
        (const __attribute__((address_space(1))) void*)g,
        (__attribute__((address_space(3))) void*)l, 16, 0, 0);
}

// ---------------------------------------------------------------------------
// convk: fp32 -> bf16, 8 elems/thread/iter, HW pack converts.
// ---------------------------------------------------------------------------
__global__ void convk(const float* __restrict__ src, u16* __restrict__ dst, int n8) {
    int i = blockIdx.x * blockDim.x + threadIdx.x;
    int st = gridDim.x * blockDim.x;
    for (; i < n8; i += st) {
        const float* p = src + (size_t)i * 8;
        f32x4 a = *(const f32x4*)p;
        f32x4 b = *(const f32x4*)(p + 4);
        i32x4 o;
        o[0] = (int)cvtpk(a[0], a[1]);
        o[1] = (int)cvtpk(a[2], a[3]);
        o[2] = (int)cvtpk(b[0], b[1]);
        o[3] = (int)cvtpk(b[2], b[3]);
        *(i32x4*)&dst[(size_t)i * 8] = o;
    }
}

// ---------------------------------------------------------------------------
// tconvk: W[R][C] fp32 -> WT[C][R] bf16.
// ---------------------------------------------------------------------------
__global__ void tconvk(const float* __restrict__ W, u16* __restrict__ WT, int R, int C) {
    int i = blockIdx.x * blockDim.x + threadIdx.x;
    if (i >= R * C) return;
    int c = i / R, r = i - c * R;
    WT[(size_t)c * R + r] = f2bf(W[(size_t)r * C + c]);
}

// ---------------------------------------------------------------------------
// gemm_bt (m97-class): C(MxN) = A(MxK) @ BT(NxK)^T, both bf16, fp32 accum.
// 128x128 tile, BK=32, 4 waves 2x2, 4x4 frags/wave, global_load_lds staging.
//   OUT_F32: fp32 out + fp32 bias/resid epilogue, else bf16 out (scaled by oscale).
//   VT_OUT:  (v-proj) write C transposed per (scene,head) with PERMUTED column
//            order g (see attn_mfma): c' = (t&0xE0)|((t&0x0C)<<1)|((t&0x10)>>2)|(t&3)
// T1 XCD swizzle: bijective remap (all grids here have nwg % 8 == 0).
// ---------------------------------------------------------------------------
template <bool OUT_F32, bool VT_OUT>
__global__ __launch_bounds__(256, 3) void gemm_bt(
    const u16* __restrict__ A, const u16* __restrict__ BT, void* __restrict__ Cv,
    int M, int N, int K,
    const float* __restrict__ bias, const float* __restrict__ resid, float oscale)
{
    __shared__ __align__(16) u16 As[128 * 32];   // 8 KB
    __shared__ __align__(16) u16 Bs[128 * 32];   // 8 KB

    const int tid  = threadIdx.x;
    const int lane = tid & 63;
    const int w    = tid >> 6;
    const int wm   = w & 1;
    const int wn   = w >> 1;

    const int nwg = gridDim.x * gridDim.y;
    const int wg  = blockIdx.y * gridDim.x + blockIdx.x;
    const int swz = (wg & 7) * (nwg >> 3) + (wg >> 3);
    const int n0  = (swz % gridDim.x) * 128;
    const int m0  = (swz / gridDim.x) * 128;

    const int l15  = lane & 15;
    const int quad = lane >> 4;

    f32x4 acc[4][4];
#pragma unroll
    for (int i = 0; i < 4; i++)
#pragma unroll
        for (int j = 0; j < 4; j++) { acc[i][j][0]=0.f; acc[i][j][1]=0.f; acc[i][j][2]=0.f; acc[i][j][3]=0.f; }

    const int sr = tid >> 2;
    const int sc = (tid & 3) * 8;
    const u16* Abase = A  + (size_t)(m0 + sr) * K + sc;
    const u16* Bbase = BT + (size_t)(n0 + sr) * K + sc;
    u16* AsD = &As[tid * 8];
    u16* BsD = &Bs[tid * 8];
    const size_t rowStep = (size_t)64 * K;

    for (int k0 = 0; k0 < K; k0 += 32) {
        gll16(Abase + k0,           AsD);
        gll16(Abase + k0 + rowStep, AsD + 2048);
        gll16(Bbase + k0,           BsD);
        gll16(Bbase + k0 + rowStep, BsD + 2048);
        __syncthreads();

        bf16x8 af[4], bfr[4];
#pragma unroll
        for (int rt = 0; rt < 4; rt++)
            af[rt] = *(const bf16x8*)&As[(wm * 64 + rt * 16 + l15) * 32 + quad * 8];
#pragma unroll
        for (int nt = 0; nt < 4; nt++)
            bfr[nt] = *(const bf16x8*)&Bs[(wn * 64 + nt * 16 + l15) * 32 + quad * 8];
#pragma unroll
        for (int rt = 0; rt < 4; rt++)
#pragma unroll
            for (int nt = 0; nt < 4; nt++)
                acc[rt][nt] = __builtin_amdgcn_mfma_f32_16x16x32_bf16(af[rt], bfr[nt], acc[rt][nt], 0, 0, 0);
        __syncthreads();
    }

    if (VT_OUT) {
        u16* CT = (u16*)Cv;
#pragma unroll
        for (int nt = 0; nt < 4; nt++) {
            int col = n0 + wn * 64 + nt * 16 + l15;   // h*64 + d
            int hh = col >> 6, dd = col & 63;
#pragma unroll
            for (int rt = 0; rt < 4; rt++) {
                int row = m0 + wm * 64 + rt * 16 + quad * 4;  // b*256 + t
                int bb = row >> 8, jb = row & 255;
                int jp = (jb & 0xE0) | ((jb & 0x0C) << 1) | ((jb & 0x10) >> 2);
                union { unsigned u[2]; i32x2 q; } pk;
                pk.u[0] = cvtpk(acc[rt][nt][0], acc[rt][nt][1]);
                pk.u[1] = cvtpk(acc[rt][nt][2], acc[rt][nt][3]);
                *(i32x2*)&CT[(((size_t)(bb * 8 + hh)) * 64 + dd) * 256 + jp] = pk.q;
            }
        }
    } else {
#pragma unroll
        for (int nt = 0; nt < 4; nt++) {
            int col = n0 + wn * 64 + nt * 16 + l15;
            float bv = bias ? bias[col] : 0.0f;
#pragma unroll
            for (int rt = 0; rt < 4; rt++) {
#pragma unroll
                for (int r = 0; r < 4; r++) {
                    int row = m0 + wm * 64 + rt * 16 + quad * 4 + r;
                    float v = acc[rt][nt][r] + bv;
                    if (resid) v += resid[(size_t)row * N + col];
                    if (OUT_F32) ((float*)Cv)[(size_t)row * N + col] = v;
                    else         ((u16*)Cv)[(size_t)row * N + col]   = f2bf(v * oscale);
                }
            }
        }
    }
}

// ---------------------------------------------------------------------------
// gemm64: 64x64 tile variant for the small K/V projections (M=2048) so the
// grid reaches 256 blocks (was 64 -> 25% of CUs). 4 waves 2x2, wave tile
// 32x32, BK=32, 2 gll16/thread/K-step. Same epilogues as gemm_bt.
// ---------------------------------------------------------------------------
template <bool OUT_F32, bool VT_OUT>
__global__ __launch_bounds__(256, 8) void gemm64(
    const u16* __restrict__ A, const u16* __restrict__ BT, void* __restrict__ Cv,
    int M, int N, int K,
    const float* __restrict__ bias, const float* __restrict__ resid, float oscale)
{
    __shared__ __align__(16) u16 As[64 * 32];   // 4 KB
    __shared__ __align__(16) u16 Bs[64 * 32];   // 4 KB

    const int tid  = threadIdx.x;
    const int lane = tid & 63;
    const int w    = tid >> 6;
    const int wm   = w & 1;
    const int wn   = w >> 1;

    const int nwg = gridDim.x * gridDim.y;
    const int wg  = blockIdx.y * gridDim.x + blockIdx.x;
    const int swz = (wg & 7) * (nwg >> 3) + (wg >> 3);
    const int n0  = (swz % gridDim.x) * 64;
    const int m0  = (swz / gridDim.x) * 64;

    const int l15  = lane & 15;
    const int quad = lane >> 4;

    f32x4 acc[2][2];
#pragma unroll
    for (int i = 0; i < 2; i++)
#pragma unroll
        for (int j = 0; j < 2; j++) { acc[i][j][0]=0.f; acc[i][j][1]=0.f; acc[i][j][2]=0.f; acc[i][j][3]=0.f; }

    const int sr = tid >> 2;          // 0..63
    const int sc = (tid & 3) * 8;
    const u16* Abase = A  + (size_t)(m0 + sr) * K + sc;
    const u16* Bbase = BT + (size_t)(n0 + sr) * K + sc;
    u16* AsD = &As[tid * 8];
    u16* BsD = &Bs[tid * 8];

    for (int k0 = 0; k0 < K; k0 += 32) {
        gll16(Abase + k0, AsD);
        gll16(Bbase + k0, BsD);
        __syncthreads();

        bf16x8 af[2], bfr[2];
#pragma unroll
        for (int rt = 0; rt < 2; rt++)
            af[rt] = *(const bf16x8*)&As[(wm * 32 + rt * 16 + l15) * 32 + quad * 8];
#pragma unroll
        for (int nt = 0; nt < 2; nt++)
            bfr[nt] = *(const bf16x8*)&Bs[(wn * 32 + nt * 16 + l15) * 32 + quad * 8];
#pragma unroll
        for (int rt = 0; rt < 2; rt++)
#pragma unroll
            for (int nt = 0; nt < 2; nt++)
                acc[rt][nt] = __builtin_amdgcn_mfma_f32_16x16x32_bf16(af[rt], bfr[nt], acc[rt][nt], 0, 0, 0);
        __syncthreads();
    }

    if (VT_OUT) {
        u16* CT = (u16*)Cv;
#pragma unroll
        for (int nt = 0; nt < 2; nt++) {
            int col = n0 + wn * 32 + nt * 16 + l15;   // h*64 + d
            int hh = col >> 6, dd = col & 63;
#pragma unroll
            for (int rt = 0; rt < 2; rt++) {
                int row = m0 + wm * 32 + rt * 16 + quad * 4;  // b*256 + t
                int bb = row >> 8, jb = row & 255;
                int jp = (jb & 0xE0) | ((jb & 0x0C) << 1) | ((jb & 0x10) >> 2);
                union { unsigned u[2]; i32x2 q; } pk;
                pk.u[0] = cvtpk(acc[rt][nt][0], acc[rt][nt][1]);
                pk.u[1] = cvtpk(acc[rt][nt][2], acc[rt][nt][3]);
                *(i32x2*)&CT[(((size_t)(bb * 8 + hh)) * 64 + dd) * 256 + jp] = pk.q;
            }
        }
    } else {
#pragma unroll
        for (int nt = 0; nt < 2; nt++) {
            int col = n0 + wn * 32 + nt * 16 + l15;
            float bv = bias ? bias[col] : 0.0f;
#pragma unroll
            for (int rt = 0; rt < 2; rt++) {
#pragma unroll
                for (int r = 0; r < 4; r++) {
                    int row = m0 + wm * 32 + rt * 16 + quad * 4 + r;
                    float v = acc[rt][nt][r] + bv;
                    if (resid) v += resid[(size_t)row * N + col];
                    if (OUT_F32) ((float*)Cv)[(size_t)row * N + col] = v;
                    else         ((u16*)Cv)[(size_t)row * N + col]   = f2bf(v * oscale);
                }
            }
        }
    }
}

// ---------------------------------------------------------------------------
// MFMA attention, zero-shuffle P path (see r2 notes).
//   S^T = mfma(K, Q); softmax lane-local in LOG2 domain (Q pre-scaled by
//   0.125*log2e in the Q-proj epilogue, so P = exp2(S' - m') directly).
//   P packed to bf16 A-frags via v_cvt_pk_bf16_f32; V columns pre-permuted
//   by bijection f in the V-proj epilogue -> PV B-frags are plain b128 reads.
//   Deferred 1/s to the O epilogue. 3 barriers. LDS 36864 B -> 4 blocks/CU.
// ---------------------------------------------------------------------------
#define KS2 72    // Ks row stride (u16)
#define VS2 264   // Vt row stride (u16)
__global__ __launch_bounds__(256, 4) void attn_mfma(
    const u16* qbuf, const u16* __restrict__ kbuf,
    const u16* __restrict__ vbufT, const int* __restrict__ perm,
    u16* ft)
{
    __shared__ __align__(16) u16 smem[18432];   // 36864 B
    u16* Ks = smem;                              // phase 1 (256 x KS2)
    u16* Vt = smem;                              // phase 3 (64 x VS2, reuse)

    const int tid   = threadIdx.x;
    const int lane  = tid & 63;
    const int w     = tid >> 6;
    const int chunk = blockIdx.x;
    const int bh    = blockIdx.y;
    const int b     = bh >> 3;
    const int h     = bh & 7;
    const int l15   = lane & 15;
    const int quad  = lane >> 4;

    // ---- Q B-frags from global (gathered row, 16B contiguous); q = w*16+l15 ----
    const int prow = perm[b * NPB + chunk * 64 + w * 16 + l15];
    const u16* qrow = qbuf + (size_t)prow * HDIM + h * HD;
    bf16x8 qf0 = *(const bf16x8*)&qrow[quad * 8];
    bf16x8 qf1 = *(const bf16x8*)&qrow[32 + quad * 8];

    // ---- stage K_h (256x64) into LDS, b128 writes ----
    {
        const int j8 = tid >> 3;        // 0..31
        const int c  = (tid & 7) * 8;   // 0..56
#pragma unroll
        for (int pass = 0; pass < 8; pass++) {
            int jj = j8 + pass * 32;
            i32x4 val = *(const i32x4*)&kbuf[((size_t)(b * KTOK + jj)) * HDIM + h * HD + c];
            *(i32x4*)&Ks[jj * KS2 + c] = val;
        }
    }
    __syncthreads();

    // ---- phase 1: S^T = K @ Q^T ----
    f32x4 sc[16];
#pragma unroll
    for (int nt = 0; nt < 16; nt++) { sc[nt][0]=0.f; sc[nt][1]=0.f; sc[nt][2]=0.f; sc[nt][3]=0.f; }
#pragma unroll
    for (int nt = 0; nt < 16; nt++) {
        bf16x8 kf = *(const bf16x8*)&Ks[(nt * 16 + l15) * KS2 + quad * 8];
        sc[nt] = __builtin_amdgcn_mfma_f32_16x16x32_bf16(kf, qf0, sc[nt], 0, 0, 0);
    }
#pragma unroll
    for (int nt = 0; nt < 16; nt++) {
        bf16x8 kf = *(const bf16x8*)&Ks[(nt * 16 + l15) * KS2 + 32 + quad * 8];
        sc[nt] = __builtin_amdgcn_mfma_f32_16x16x32_bf16(kf, qf1, sc[nt], 0, 0, 0);
    }
    // sc[nt][r] = S'[k = nt*16 + quad*4 + r][q = w*16 + l15]  (log2-domain scores)

    // ---- phase 3a: issue V' loads to regs; latency hides under softmax ----
    i32x4 vreg[8];
    const u16* vslice = vbufT + ((size_t)(b * NHEAD + h)) * HD * KTOK;
    const int vrow = tid >> 2;          // d = 0..63
    const int vc0  = (tid & 3) * 8;
#pragma unroll
    for (int pass = 0; pass < 8; pass++)
        vreg[pass] = *(const i32x4*)&vslice[(size_t)vrow * KTOK + vc0 + pass * 32];

    // ---- phase 2: softmax (log2 domain), lane-local; deferred 1/s ----
    float m = -1e30f;
#pragma unroll
    for (int nt = 0; nt < 16; nt++) {
        f32x4 v = sc[nt];
        m = fmaxf(m, fmaxf(fmaxf(v[0], v[1]), fmaxf(v[2], v[3])));
    }
    m = fmaxf(m, __shfl_xor(m, 16));
    m = fmaxf(m, __shfl_xor(m, 32));
    float s0 = 0.f, s1 = 0.f, s2 = 0.f, s3 = 0.f;
#pragma unroll
    for (int nt = 0; nt < 16; nt++) {
        float e0 = exp2_hw(sc[nt][0] - m);
        float e1 = exp2_hw(sc[nt][1] - m);
        float e2 = exp2_hw(sc[nt][2] - m);
        float e3 = exp2_hw(sc[nt][3] - m);
        sc[nt][0] = e0; sc[nt][1] = e1; sc[nt][2] = e2; sc[nt][3] = e3;
        s0 += e0; s1 += e1; s2 += e2; s3 += e3;
    }
    float s = (s0 + s1) + (s2 + s3);
    s += __shfl_xor(s, 16);
    s += __shfl_xor(s, 32);
    float inv = 1.0f / s;

    // ---- pack P to bf16 pairs in-register (HW cvt_pk) ----
    unsigned up[16][2];
#pragma unroll
    for (int nt = 0; nt < 16; nt++) {
        up[nt][0] = cvtpk(sc[nt][0], sc[nt][1]);
        up[nt][1] = cvtpk(sc[nt][2], sc[nt][3]);
    }

    __syncthreads();   // all waves done reading Ks; region becomes Vt'

    // ---- phase 3b: store Vt' rows to LDS (contiguous b128) ----
#pragma unroll
    for (int pass = 0; pass < 8; pass++)
        *(i32x4*)&Vt[vrow * VS2 + vc0 + pass * 32] = vreg[pass];
    __syncthreads();

    // ---- phase 4: O = P V (A = P regs, B = Vt' b128 reads; 32 MFMA) ----
    f32x4 o[4];
#pragma unroll
    for (int n = 0; n < 4; n++) { o[n][0]=0.f; o[n][1]=0.f; o[n][2]=0.f; o[n][3]=0.f; }

#pragma unroll
    for (int ks = 0; ks < 8; ks++) {
        union { unsigned u[4]; bf16x8 v; } pb;
        pb.u[0] = up[2 * ks][0];
        pb.u[1] = up[2 * ks][1];
        pb.u[2] = up[2 * ks + 1][0];
        pb.u[3] = up[2 * ks + 1][1];
#pragma unroll
        for (int nt = 0; nt < 4; nt++) {
            bf16x8 bv = *(const bf16x8*)&Vt[(nt * 16 + l15) * VS2 + ks * 32 + quad * 8];
            o[nt] = __builtin_amdgcn_mfma_f32_16x16x32_bf16(pb.v, bv, o[nt], 0, 0, 0);
        }
    }
    // o[nt][r] = O~[q = w*16 + quad*4 + r][d = nt*16 + l15]  (unnormalized)

    // ---- phase 5: normalize + scatter O rows to ft[perm[q]] ----
#pragma unroll
    for (int r = 0; r < 4; r++) {
        float invq = __shfl(inv,  quad * 4 + r);
        int   po   = __shfl(prow, quad * 4 + r);
        u16* frow = ft + (size_t)po * HDIM + h * HD;
        unsigned pa = cvtpk(o[0][r] * invq, o[1][r] * invq);
        unsigned pb = cvtpk(o[2][r] * invq, o[3][r] * invq);
        frow[l15]      = (u16)pa;
        frow[16 + l15] = (u16)(pa >> 16);
        frow[32 + l15] = (u16)pb;
        frow[48 + l15] = (u16)(pb >> 16);
    }
}

// ---------------------------------------------------------------------------
// Launch. Workspace (unchanged 71303168 B):
//   ws+0        kbuf  [2048][512] bf16          (2 MB)
//   ws+2097152  vbufT [b][h][d][c'] bf16        (2 MB)  -> WoutT after attn
//   ws+4194304  qbuf/ft [65536][512] bf16       (67 MB)
// Scratch in d_out (all dead before the final gemm writes d_out):
//   +0 xb (33.5 MB), +33554432 cb (3 MB), +36700160 WqT, +36962304 WkT,
//   +37748736 WvT (ends 38535168 < 67108864)
// ---------------------------------------------------------------------------
extern "C" void kernel_launch(void* const* d_in, const int* in_sizes, int n_in,
                              void* d_out, int out_size, void* d_ws, size_t ws_size,
                              hipStream_t stream) {
    const float* xF      = (const float*)d_in[0];
    const float* context = (const float*)d_in[1];
    const int*   perm    = (const int*)d_in[2];
    const float* Wq      = (const float*)d_in[3];
    const float* Wk      = (const float*)d_in[4];
    const float* Wv      = (const float*)d_in[5];
    const float* Wout    = (const float*)d_in[6];
    const float* b_out   = (const float*)d_in[7];
    float*       out     = (float*)d_out;

    const size_t WS_NEED = 71303168ULL;
    if (ws_size < WS_NEED) {
        hipMemsetAsync(d_out, 0, (size_t)out_size * sizeof(float), stream);
        return;
    }
    char* ws    = (char*)d_ws;
    u16* kbuf   = (u16*)(ws + 0);
    u16* vbufT  = (u16*)(ws + 2097152);
    u16* qbuf   = (u16*)(ws + 4194304);
    u16* ft     = qbuf;                         // aliased (see attn_mfma comment)
    u16* WoutT  = (u16*)(ws + 2097152);         // overwrites vbufT AFTER attn

    char* ob    = (char*)d_out;                 // d_out as pre-attn scratch
    u16* xb     = (u16*)(ob + 0);
    u16* cb     = (u16*)(ob + 33554432);
    u16* WqT    = (u16*)(ob + 36700160);
    u16* WkT    = (u16*)(ob + 36962304);
    u16* WvT    = (u16*)(ob + 37748736);

    // ---- prep: bf16 conversions / weight transposes ----
    convk<<<2048, 256, 0, stream>>>(xF, xb, N_PTS * CH_DIM / 8);
    convk<<<768, 256, 0, stream>>>(context, cb, BATCH * KTOK * CTX_DIM / 8);
    tconvk<<<(CH_DIM * HDIM + 255) / 256, 256, 0, stream>>>(Wq, WqT, CH_DIM, HDIM);
    tconvk<<<(CTX_DIM * HDIM + 255) / 256, 256, 0, stream>>>(Wk, WkT, CTX_DIM, HDIM);
    tconvk<<<(CTX_DIM * HDIM + 255) / 256, 256, 0, stream>>>(Wv, WvT, CTX_DIM, HDIM);

    // ---- projections; Q pre-scaled by D^-0.5 * log2(e) (log2-domain softmax) ----
    gemm_bt<false, false><<<dim3(HDIM / 128, N_PTS / 128), 256, 0, stream>>>(
        xb, WqT, qbuf, N_PTS, HDIM, CH_DIM, nullptr, nullptr, 0.1803368801f);
    gemm64<false, false><<<dim3(HDIM / 64, (BATCH * KTOK) / 64), 256, 0, stream>>>(
        cb, WkT, kbuf, BATCH * KTOK, HDIM, CTX_DIM, nullptr, nullptr, 1.0f);
    gemm64<false, true><<<dim3(HDIM / 64, (BATCH * KTOK) / 64), 256, 0, stream>>>(
        cb, WvT, vbufT, BATCH * KTOK, HDIM, CTX_DIM, nullptr, nullptr, 1.0f);

    // ---- attention ----
    attn_mfma<<<dim3(NPB / 64, BATCH * NHEAD), 256, 0, stream>>>(
        qbuf, kbuf, vbufT, perm, ft);

    // ---- out projection (+bias+residual, fp32 out) ----
    tconvk<<<(HDIM * CH_DIM + 255) / 256, 256, 0, stream>>>(Wout, WoutT, HDIM, CH_DIM);
    gemm_bt<true, false><<<dim3(CH_DIM / 128, N_PTS / 128), 256, 0, stream>>>(
        ft, WoutT, out, N_PTS, CH_DIM, HDIM, b_out, xF, 1.0f);
}

// Round 4
// 301.159 us; speedup vs baseline: 1.4858x; 1.0034x over previous
//
#include <hip/hip_runtime.h>

typedef unsigned short u16;
typedef __attribute__((ext_vector_type(8))) short bf16x8;
typedef __attribute__((ext_vector_type(4))) float f32x4;
typedef __attribute__((ext_vector_type(4))) int i32x4;
typedef __attribute__((ext_vector_type(2))) int i32x2;

#define N_PTS   65536
#define CH_DIM  256
#define BATCH   8
#define KTOK    256
#define CTX_DIM 768
#define NHEAD   8
#define HD      64
#define HDIM    512   // NHEAD*HD
#define NPB     8192  // N_PTS/BATCH

__device__ __forceinline__ u16 f2bf(float f) {
    union { float f; unsigned u; } v; v.f = f;
    unsigned r = v.u + 0x7fffu + ((v.u >> 16) & 1u);
    return (u16)(r >> 16);
}
// HW packed f32->bf16 (RNE), 1 instr for a pair.
__device__ __forceinline__ unsigned cvtpk(float lo, float hi) {
    unsigned r;
    asm("v_cvt_pk_bf16_f32 %0, %1, %2" : "=v"(r) : "v"(lo), "v"(hi));
    return r;
}
// bare v_exp_f32 (base-2 exponential)
__device__ __forceinline__ float exp2_hw(float x) {
    float r;
    asm("v_exp_f32 %0, %1" : "=v"(r) : "v"(x));
    return r;
}
__device__ __forceinline__ float max3f(float a, float b, float c) {
    float r;
    asm("v_max3_f32 %0, %1, %2, %3" : "=v"(r) : "v"(a), "v"(b), "v"(c));
    return r;
}

// async global->LDS, 16B per lane. HW writes lane i at wave-uniform base + i*16.
__device__ __forceinline__ void gll16(const void* g, void* l) {
    __builtin_amdgcn_global_load_lds(
        (const __attribute__((address_space(1))) void*)g,
        (__attribute__((address_space(3))) void*)l, 16, 0, 0);
}

// ---------------------------------------------------------------------------
// convk: fp32 -> bf16, 8 elems/thread/iter, HW pack converts.
// ---------------------------------------------------------------------------
__global__ void convk(const float* __restrict__ src, u16* __restrict__ dst, int n8) {
    int i = blockIdx.x * blockDim.x + threadIdx.x;
    int st = gridDim.x * blockDim.x;
    for (; i < n8; i += st) {
        const float* p = src + (size_t)i * 8;
        f32x4 a = *(const f32x4*)p;
        f32x4 b = *(const f32x4*)(p + 4);
        i32x4 o;
        o[0] = (int)cvtpk(a[0], a[1]);
        o[1] = (int)cvtpk(a[2], a[3]);
        o[2] = (int)cvtpk(b[0], b[1]);
        o[3] = (int)cvtpk(b[2], b[3]);
        *(i32x4*)&dst[(size_t)i * 8] = o;
    }
}

// ---------------------------------------------------------------------------
// tconvk: W[R][C] fp32 -> WT[C][R] bf16.
// ---------------------------------------------------------------------------
__global__ void tconvk(const float* __restrict__ W, u16* __restrict__ WT, int R, int C) {
    int i = blockIdx.x * blockDim.x + threadIdx.x;
    if (i >= R * C) return;
    int c = i / R, r = i - c * R;
    WT[(size_t)c * R + r] = f2bf(W[(size_t)r * C + c]);
}

// ---------------------------------------------------------------------------
// gemm_bt, 2-phase pipelined (T3-minimum): C(MxN) = A(MxK) @ BT(NxK)^T.
// 128x128 tile, BK=32, 4 waves 2x2, 4x4 frags/wave.
// Double-buffered LDS; issue next tile's global_load_lds BEFORE computing the
// current tile; raw s_barrier + hand-placed vmcnt(0) AFTER the MFMAs so the
// HBM latency of the prefetch hides under compute (no __syncthreads drain).
// sched_barrier(0) pins the barrier region (rule #18).
//   OUT_F32: fp32 out + fp32 bias/resid epilogue, else bf16 out (scaled by oscale).
//   VT_OUT:  (v-proj) transposed+permuted C write (see attn_mfma).
// T1 XCD swizzle: bijective remap (all grids here have nwg % 8 == 0).
// ---------------------------------------------------------------------------
template <bool OUT_F32, bool VT_OUT>
__global__ __launch_bounds__(256, 3) void gemm_bt(
    const u16* __restrict__ A, const u16* __restrict__ BT, void* __restrict__ Cv,
    int M, int N, int K,
    const float* __restrict__ bias, const float* __restrict__ resid, float oscale)
{
    __shared__ __align__(16) u16 As[2][128 * 32];   // 2 x 8 KB
    __shared__ __align__(16) u16 Bs[2][128 * 32];   // 2 x 8 KB

    const int tid  = threadIdx.x;
    const int lane = tid & 63;
    const int w    = tid >> 6;
    const int wm   = w & 1;
    const int wn   = w >> 1;

    const int nwg = gridDim.x * gridDim.y;
    const int wg  = blockIdx.y * gridDim.x + blockIdx.x;
    const int swz = (wg & 7) * (nwg >> 3) + (wg >> 3);
    const int n0  = (swz % gridDim.x) * 128;
    const int m0  = (swz / gridDim.x) * 128;

    const int l15  = lane & 15;
    const int quad = lane >> 4;

    f32x4 acc[4][4];
#pragma unroll
    for (int i = 0; i < 4; i++)
#pragma unroll
        for (int j = 0; j < 4; j++) { acc[i][j][0]=0.f; acc[i][j][1]=0.f; acc[i][j][2]=0.f; acc[i][j][3]=0.f; }

    const int sr = tid >> 2;
    const int sc = (tid & 3) * 8;
    const u16* Abase = A  + (size_t)(m0 + sr) * K + sc;
    const u16* Bbase = BT + (size_t)(n0 + sr) * K + sc;
    const size_t rowStep = (size_t)64 * K;
    const int d8 = tid * 8;

    // ---- prologue: stage tile 0 into buffer 0 ----
    gll16(Abase,           &As[0][d8]);
    gll16(Abase + rowStep, &As[0][d8 + 2048]);
    gll16(Bbase,           &Bs[0][d8]);
    gll16(Bbase + rowStep, &Bs[0][d8 + 2048]);
    asm volatile("s_waitcnt vmcnt(0)" ::: "memory");
    __builtin_amdgcn_s_barrier();
    __builtin_amdgcn_sched_barrier(0);

    const int ntile = K >> 5;
    int cur = 0;
    for (int t = 0; t < ntile; ++t) {
        if (t + 1 < ntile) {                     // uniform branch
            const u16* An = Abase + ((t + 1) << 5);
            const u16* Bn = Bbase + ((t + 1) << 5);
            const int nxt = cur ^ 1;
            gll16(An,           &As[nxt][d8]);
            gll16(An + rowStep, &As[nxt][d8 + 2048]);
            gll16(Bn,           &Bs[nxt][d8]);
            gll16(Bn + rowStep, &Bs[nxt][d8 + 2048]);
        }
        bf16x8 af[4], bfr[4];
#pragma unroll
        for (int rt = 0; rt < 4; rt++)
            af[rt] = *(const bf16x8*)&As[cur][(wm * 64 + rt * 16 + l15) * 32 + quad * 8];
#pragma unroll
        for (int nt = 0; nt < 4; nt++)
            bfr[nt] = *(const bf16x8*)&Bs[cur][(wn * 64 + nt * 16 + l15) * 32 + quad * 8];
#pragma unroll
        for (int rt = 0; rt < 4; rt++)
#pragma unroll
            for (int nt = 0; nt < 4; nt++)
                acc[rt][nt] = __builtin_amdgcn_mfma_f32_16x16x32_bf16(af[rt], bfr[nt], acc[rt][nt], 0, 0, 0);
        asm volatile("s_waitcnt vmcnt(0)" ::: "memory");   // prefetch landed
        __builtin_amdgcn_sched_barrier(0);
        __builtin_amdgcn_s_barrier();                       // all waves done with buf[cur]
        __builtin_amdgcn_sched_barrier(0);
        cur ^= 1;
    }

    if (VT_OUT) {
        u16* CT = (u16*)Cv;
#pragma unroll
        for (int nt = 0; nt < 4; nt++) {
            int col = n0 + wn * 64 + nt * 16 + l15;   // h*64 + d
            int hh = col >> 6, dd = col & 63;
#pragma unroll
            for (int rt = 0; rt < 4; rt++) {
                int row = m0 + wm * 64 + rt * 16 + quad * 4;  // b*256 + t
                int bb = row >> 8, jb = row & 255;
                int jp = (jb & 0xE0) | ((jb & 0x0C) << 1) | ((jb & 0x10) >> 2);
                union { unsigned u[2]; i32x2 q; } pk;
                pk.u[0] = cvtpk(acc[rt][nt][0], acc[rt][nt][1]);
                pk.u[1] = cvtpk(acc[rt][nt][2], acc[rt][nt][3]);
                *(i32x2*)&CT[(((size_t)(bb * 8 + hh)) * 64 + dd) * 256 + jp] = pk.q;
            }
        }
    } else {
#pragma unroll
        for (int nt = 0; nt < 4; nt++) {
            int col = n0 + wn * 64 + nt * 16 + l15;
            float bv = bias ? bias[col] : 0.0f;
#pragma unroll
            for (int rt = 0; rt < 4; rt++) {
#pragma unroll
                for (int r = 0; r < 4; r++) {
                    int row = m0 + wm * 64 + rt * 16 + quad * 4 + r;
                    float v = acc[rt][nt][r] + bv;
                    if (resid) v += resid[(size_t)row * N + col];
                    if (OUT_F32) ((float*)Cv)[(size_t)row * N + col] = v;
                    else         ((u16*)Cv)[(size_t)row * N + col]   = f2bf(v * oscale);
                }
            }
        }
    }
}

// ---------------------------------------------------------------------------
// gemm_kv: fused K-proj + V-proj. A = cb [2048][768], BT = WkvT [1024][768]
// (rows 0..511 = WkT, 512..1023 = WvT). 64x64 tile, 4 waves 2x2, BK=32,
// 2-phase pipelined like gemm_bt. Grid 16x32 = 512 blocks -> 2 blocks/CU
// (was 2 x 256-block launches at 1 block/CU). Epilogue branch is
// block-uniform (n0 multiple of 64; 512 % 64 == 0):
//   n0 <  512 -> kbuf[row*512 + col]
//   n0 >= 512 -> vbufT transposed+permuted write (same math as before).
// ---------------------------------------------------------------------------
__global__ __launch_bounds__(256, 4) void gemm_kv(
    const u16* __restrict__ A, const u16* __restrict__ BT,
    u16* __restrict__ kd, u16* __restrict__ vtd)
{
    __shared__ __align__(16) u16 As[2][64 * 32];   // 2 x 4 KB
    __shared__ __align__(16) u16 Bs[2][64 * 32];   // 2 x 4 KB
    const int K = CTX_DIM;

    const int tid  = threadIdx.x;
    const int lane = tid & 63;
    const int w    = tid >> 6;
    const int wm   = w & 1;
    const int wn   = w >> 1;

    const int nwg = gridDim.x * gridDim.y;          // 512
    const int wg  = blockIdx.y * gridDim.x + blockIdx.x;
    const int swz = (wg & 7) * (nwg >> 3) + (wg >> 3);
    const int n0  = (swz % gridDim.x) * 64;
    const int m0  = (swz / gridDim.x) * 64;

    const int l15  = lane & 15;
    const int quad = lane >> 4;

    f32x4 acc[2][2];
#pragma unroll
    for (int i = 0; i < 2; i++)
#pragma unroll
        for (int j = 0; j < 2; j++) { acc[i][j][0]=0.f; acc[i][j][1]=0.f; acc[i][j][2]=0.f; acc[i][j][3]=0.f; }

    const int sr = tid >> 2;          // 0..63
    const int sc = (tid & 3) * 8;
    const u16* Abase = A  + (size_t)(m0 + sr) * K + sc;
    const u16* Bbase = BT + (size_t)(n0 + sr) * K + sc;
    const int d8 = tid * 8;

    gll16(Abase, &As[0][d8]);
    gll16(Bbase, &Bs[0][d8]);
    asm volatile("s_waitcnt vmcnt(0)" ::: "memory");
    __builtin_amdgcn_s_barrier();
    __builtin_amdgcn_sched_barrier(0);

    const int ntile = K >> 5;   // 24
    int cur = 0;
    for (int t = 0; t < ntile; ++t) {
        if (t + 1 < ntile) {
            const int nxt = cur ^ 1;
            gll16(Abase + ((t + 1) << 5), &As[nxt][d8]);
            gll16(Bbase + ((t + 1) << 5), &Bs[nxt][d8]);
        }
        bf16x8 af[2], bfr[2];
#pragma unroll
        for (int rt = 0; rt < 2; rt++)
            af[rt] = *(const bf16x8*)&As[cur][(wm * 32 + rt * 16 + l15) * 32 + quad * 8];
#pragma unroll
        for (int nt = 0; nt < 2; nt++)
            bfr[nt] = *(const bf16x8*)&Bs[cur][(wn * 32 + nt * 16 + l15) * 32 + quad * 8];
#pragma unroll
        for (int rt = 0; rt < 2; rt++)
#pragma unroll
            for (int nt = 0; nt < 2; nt++)
                acc[rt][nt] = __builtin_amdgcn_mfma_f32_16x16x32_bf16(af[rt], bfr[nt], acc[rt][nt], 0, 0, 0);
        asm volatile("s_waitcnt vmcnt(0)" ::: "memory");
        __builtin_amdgcn_sched_barrier(0);
        __builtin_amdgcn_s_barrier();
        __builtin_amdgcn_sched_barrier(0);
        cur ^= 1;
    }

    if (n0 < 512) {   // ---- K half: plain bf16 [2048][512] ----
#pragma unroll
        for (int nt = 0; nt < 2; nt++) {
            int col = n0 + wn * 32 + nt * 16 + l15;
#pragma unroll
            for (int rt = 0; rt < 2; rt++) {
#pragma unroll
                for (int r = 0; r < 4; r++) {
                    int row = m0 + wm * 32 + rt * 16 + quad * 4 + r;
                    kd[(size_t)row * HDIM + col] = f2bf(acc[rt][nt][r]);
                }
            }
        }
    } else {          // ---- V half: transposed + permuted (attn PV layout) ----
#pragma unroll
        for (int nt = 0; nt < 2; nt++) {
            int col = (n0 - 512) + wn * 32 + nt * 16 + l15;   // h*64 + d
            int hh = col >> 6, dd = col & 63;
#pragma unroll
            for (int rt = 0; rt < 2; rt++) {
                int row = m0 + wm * 32 + rt * 16 + quad * 4;  // b*256 + t
                int bb = row >> 8, jb = row & 255;
                int jp = (jb & 0xE0) | ((jb & 0x0C) << 1) | ((jb & 0x10) >> 2);
                union { unsigned u[2]; i32x2 q; } pk;
                pk.u[0] = cvtpk(acc[rt][nt][0], acc[rt][nt][1]);
                pk.u[1] = cvtpk(acc[rt][nt][2], acc[rt][nt][3]);
                *(i32x2*)&vtd[(((size_t)(bb * 8 + hh)) * 64 + dd) * 256 + jp] = pk.q;
            }
        }
    }
}

// ---------------------------------------------------------------------------
// MFMA attention, zero-shuffle P path (see r2/r3 notes).
//   S^T = mfma(K, Q); softmax lane-local in LOG2 domain (Q pre-scaled by
//   0.125*log2e); P packed to bf16 A-frags via v_cvt_pk_bf16_f32; V columns
//   pre-permuted by bijection f -> PV B-frags are plain b128 reads.
//   Deferred 1/s. 3 barriers. LDS 36864 B -> 4 blocks/CU. max3 max-reduce.
// ---------------------------------------------------------------------------
#define KS2 72    // Ks row stride (u16)
#define VS2 264   // Vt row stride (u16)
__global__ __launch_bounds__(256, 4) void attn_mfma(
    const u16* qbuf, const u16* __restrict__ kbuf,
    const u16* __restrict__ vbufT, const int* __restrict__ perm,
    u16* ft)
{
    __shared__ __align__(16) u16 smem[18432];   // 36864 B
    u16* Ks = smem;                              // phase 1 (256 x KS2)
    u16* Vt = smem;                              // phase 3 (64 x VS2, reuse)

    const int tid   = threadIdx.x;
    const int lane  = tid & 63;
    const int w     = tid >> 6;
    const int chunk = blockIdx.x;
    const int bh    = blockIdx.y;
    const int b     = bh >> 3;
    const int h     = bh & 7;
    const int l15   = lane & 15;
    const int quad  = lane >> 4;

    // ---- Q B-frags from global (gathered row, 16B contiguous); q = w*16+l15 ----
    const int prow = perm[b * NPB + chunk * 64 + w * 16 + l15];
    const u16* qrow = qbuf + (size_t)prow * HDIM + h * HD;
    bf16x8 qf0 = *(const bf16x8*)&qrow[quad * 8];
    bf16x8 qf1 = *(const bf16x8*)&qrow[32 + quad * 8];

    // ---- stage K_h (256x64) into LDS, b128 writes ----
    {
        const int j8 = tid >> 3;        // 0..31
        const int c  = (tid & 7) * 8;   // 0..56
#pragma unroll
        for (int pass = 0; pass < 8; pass++) {
            int jj = j8 + pass * 32;
            i32x4 val = *(const i32x4*)&kbuf[((size_t)(b * KTOK + jj)) * HDIM + h * HD + c];
            *(i32x4*)&Ks[jj * KS2 + c] = val;
        }
    }
    __syncthreads();

    // ---- phase 1: S^T = K @ Q^T ----
    f32x4 sc[16];
#pragma unroll
    for (int nt = 0; nt < 16; nt++) { sc[nt][0]=0.f; sc[nt][1]=0.f; sc[nt][2]=0.f; sc[nt][3]=0.f; }
#pragma unroll
    for (int nt = 0; nt < 16; nt++) {
        bf16x8 kf = *(const bf16x8*)&Ks[(nt * 16 + l15) * KS2 + quad * 8];
        sc[nt] = __builtin_amdgcn_mfma_f32_16x16x32_bf16(kf, qf0, sc[nt], 0, 0, 0);
    }
#pragma unroll
    for (int nt = 0; nt < 16; nt++) {
        bf16x8 kf = *(const bf16x8*)&Ks[(nt * 16 + l15) * KS2 + 32 + quad * 8];
        sc[nt] = __builtin_amdgcn_mfma_f32_16x16x32_bf16(kf, qf1, sc[nt], 0, 0, 0);
    }
    // sc[nt][r] = S'[k = nt*16 + quad*4 + r][q = w*16 + l15]  (log2-domain)

    // ---- phase 3a: issue V' loads to regs; latency hides under softmax ----
    i32x4 vreg[8];
    const u16* vslice = vbufT + ((size_t)(b * NHEAD + h)) * HD * KTOK;
    const int vrow = tid >> 2;          // d = 0..63
    const int vc0  = (tid & 3) * 8;
#pragma unroll
    for (int pass = 0; pass < 8; pass++)
        vreg[pass] = *(const i32x4*)&vslice[(size_t)vrow * KTOK + vc0 + pass * 32];

    // ---- phase 2: softmax (log2 domain), lane-local; deferred 1/s ----
    float m = -1e30f;
#pragma unroll
    for (int nt = 0; nt < 16; nt++) {
        f32x4 v = sc[nt];
        m = max3f(m, max3f(v[0], v[1], v[2]), v[3]);
    }
    m = fmaxf(m, __shfl_xor(m, 16));
    m = fmaxf(m, __shfl_xor(m, 32));
    float s0 = 0.f, s1 = 0.f, s2 = 0.f, s3 = 0.f;
#pragma unroll
    for (int nt = 0; nt < 16; nt++) {
        float e0 = exp2_hw(sc[nt][0] - m);
        float e1 = exp2_hw(sc[nt][1] - m);
        float e2 = exp2_hw(sc[nt][2] - m);
        float e3 = exp2_hw(sc[nt][3] - m);
        sc[nt][0] = e0; sc[nt][1] = e1; sc[nt][2] = e2; sc[nt][3] = e3;
        s0 += e0; s1 += e1; s2 += e2; s3 += e3;
    }
    float s = (s0 + s1) + (s2 + s3);
    s += __shfl_xor(s, 16);
    s += __shfl_xor(s, 32);
    float inv = 1.0f / s;

    // ---- pack P to bf16 pairs in-register (HW cvt_pk) ----
    unsigned up[16][2];
#pragma unroll
    for (int nt = 0; nt < 16; nt++) {
        up[nt][0] = cvtpk(sc[nt][0], sc[nt][1]);
        up[nt][1] = cvtpk(sc[nt][2], sc[nt][3]);
    }

    __syncthreads();   // all waves done reading Ks; region becomes Vt'

    // ---- phase 3b: store Vt' rows to LDS (contiguous b128) ----
#pragma unroll
    for (int pass = 0; pass < 8; pass++)
        *(i32x4*)&Vt[vrow * VS2 + vc0 + pass * 32] = vreg[pass];
    __syncthreads();

    // ---- phase 4: O = P V (A = P regs, B = Vt' b128 reads; 32 MFMA) ----
    f32x4 o[4];
#pragma unroll
    for (int n = 0; n < 4; n++) { o[n][0]=0.f; o[n][1]=0.f; o[n][2]=0.f; o[n][3]=0.f; }

#pragma unroll
    for (int ks = 0; ks < 8; ks++) {
        union { unsigned u[4]; bf16x8 v; } pb;
        pb.u[0] = up[2 * ks][0];
        pb.u[1] = up[2 * ks][1];
        pb.u[2] = up[2 * ks + 1][0];
        pb.u[3] = up[2 * ks + 1][1];
#pragma unroll
        for (int nt = 0; nt < 4; nt++) {
            bf16x8 bv = *(const bf16x8*)&Vt[(nt * 16 + l15) * VS2 + ks * 32 + quad * 8];
            o[nt] = __builtin_amdgcn_mfma_f32_16x16x32_bf16(pb.v, bv, o[nt], 0, 0, 0);
        }
    }
    // o[nt][r] = O~[q = w*16 + quad*4 + r][d = nt*16 + l15]  (unnormalized)

    // ---- phase 5: normalize + scatter O rows to ft[perm[q]] ----
#pragma unroll
    for (int r = 0; r < 4; r++) {
        float invq = __shfl(inv,  quad * 4 + r);
        int   po   = __shfl(prow, quad * 4 + r);
        u16* frow = ft + (size_t)po * HDIM + h * HD;
        unsigned pa = cvtpk(o[0][r] * invq, o[1][r] * invq);
        unsigned pb = cvtpk(o[2][r] * invq, o[3][r] * invq);
        frow[l15]      = (u16)pa;
        frow[16 + l15] = (u16)(pa >> 16);
        frow[32 + l15] = (u16)pb;
        frow[48 + l15] = (u16)(pb >> 16);
    }
}

// ---------------------------------------------------------------------------
// Launch. Workspace (unchanged 71303168 B):
//   ws+0        kbuf  [2048][512] bf16          (2 MB)
//   ws+2097152  vbufT [b][h][d][c'] bf16        (2 MB)  -> WoutT after attn
//   ws+4194304  qbuf/ft [65536][512] bf16       (67 MB)
// Scratch in d_out (all dead before the final gemm writes d_out):
//   +0         xb   [65536][256] bf16  (33554432)
//   +33554432  cb   [2048][768]  bf16  (3145728, ends 36700160)
//   +36700160  WkvT [1024][768]  bf16  (1572864, ends 38273024)
//   +38273024  WqT  [512][256]   bf16  (262144,  ends 38535168 < 67108864)
// ---------------------------------------------------------------------------
extern "C" void kernel_launch(void* const* d_in, const int* in_sizes, int n_in,
                              void* d_out, int out_size, void* d_ws, size_t ws_size,
                              hipStream_t stream) {
    const float* xF      = (const float*)d_in[0];
    const float* context = (const float*)d_in[1];
    const int*   perm    = (const int*)d_in[2];
    const float* Wq      = (const float*)d_in[3];
    const float* Wk      = (const float*)d_in[4];
    const float* Wv      = (const float*)d_in[5];
    const float* Wout    = (const float*)d_in[6];
    const float* b_out   = (const float*)d_in[7];
    float*       out     = (float*)d_out;

    const size_t WS_NEED = 71303168ULL;
    if (ws_size < WS_NEED) {
        hipMemsetAsync(d_out, 0, (size_t)out_size * sizeof(float), stream);
        return;
    }
    char* ws    = (char*)d_ws;
    u16* kbuf   = (u16*)(ws + 0);
    u16* vbufT  = (u16*)(ws + 2097152);
    u16* qbuf   = (u16*)(ws + 4194304);
    u16* ft     = qbuf;                         // aliased (see attn_mfma comment)
    u16* WoutT  = (u16*)(ws + 2097152);         // overwrites vbufT AFTER attn

    char* ob    = (char*)d_out;                 // d_out as pre-attn scratch
    u16* xb     = (u16*)(ob + 0);
    u16* cb     = (u16*)(ob + 33554432);
    u16* WkvT   = (u16*)(ob + 36700160);        // [1024][768]: rows 0-511 K, 512-1023 V
    u16* WqT    = (u16*)(ob + 38273024);

    // ---- prep: bf16 conversions / weight transposes ----
    convk<<<2048, 256, 0, stream>>>(xF, xb, N_PTS * CH_DIM / 8);
    convk<<<768, 256, 0, stream>>>(context, cb, BATCH * KTOK * CTX_DIM / 8);
    tconvk<<<(CH_DIM * HDIM + 255) / 256, 256, 0, stream>>>(Wq, WqT, CH_DIM, HDIM);
    tconvk<<<(CTX_DIM * HDIM + 255) / 256, 256, 0, stream>>>(Wk, WkvT, CTX_DIM, HDIM);
    tconvk<<<(CTX_DIM * HDIM + 255) / 256, 256, 0, stream>>>(Wv, WkvT + 512 * 768, CTX_DIM, HDIM);

    // ---- projections; Q pre-scaled by D^-0.5 * log2(e) (log2-domain softmax) ----
    gemm_bt<false, false><<<dim3(HDIM / 128, N_PTS / 128), 256, 0, stream>>>(
        xb, WqT, qbuf, N_PTS, HDIM, CH_DIM, nullptr, nullptr, 0.1803368801f);
    gemm_kv<<<dim3(16, 32), 256, 0, stream>>>(cb, WkvT, kbuf, vbufT);

    // ---- attention ----
    attn_mfma<<<dim3(NPB / 64, BATCH * NHEAD), 256, 0, stream>>>(
        qbuf, kbuf, vbufT, perm, ft);

    // ---- out projection (+bias+residual, fp32 out) ----
    tconvk<<<(HDIM * CH_DIM + 255) / 256, 256, 0, stream>>>(Wout, WoutT, HDIM, CH_DIM);
    gemm_bt<true, false><<<dim3(CH_DIM / 128, N_PTS / 128), 256, 0, stream>>>(
        ft, WoutT, out, N_PTS, CH_DIM, HDIM, b_out, xF, 1.0f);
}